// Round 1
// baseline (129.515 us; speedup 1.0000x reference)
//
#include <hip/hip_runtime.h>

#define BS     4096
#define HIDDEN 2048
#define MAXR   16
#define NSLOT  8
#define NMOD   2
#define OUTW   8192

// ---------------------------------------------------------------------------
// Kernel 1: shrink. inter[m][i][r] = sum_h x[sorted_ids[i]][h] * A[m,s,h,r]
// rank-masked to zero for r >= slot_ranks[s].
// Block = 4 consecutive rows (same slot; slot groups are 512 rows, 4 | 512).
// Thread t: r = t&15, g = t>>4; h = 16*k + g  ->  A read is Ap[256k + t]
// (fully coalesced, 1 KiB per wave-instr), LDS x read is a 16-lane broadcast
// of 16 consecutive addresses (conflict-free).
// ---------------------------------------------------------------------------
__global__ __launch_bounds__(256) void lora_shrink(
    const float* __restrict__ x,
    const float* __restrict__ A,
    const int*   __restrict__ sorted_ids,
    const int*   __restrict__ slot_ranks,
    const int*   __restrict__ slot_offsets,
    float*       __restrict__ inter)
{
    const int ROWS = 4;
    const int i0 = blockIdx.x * ROWS;
    const int t  = threadIdx.x;

    int s = 0;
    #pragma unroll
    for (int k = 1; k < NSLOT; ++k) if (i0 >= slot_offsets[k]) s = k;
    const int R = slot_ranks[s];

    __shared__ float xs[ROWS][HIDDEN];      // 32 KiB
    __shared__ float red[4][ROWS][MAXR];    // 1 KiB

    // stage 4 gathered x rows into LDS with float4 loads
    #pragma unroll
    for (int j = 0; j < ROWS; ++j) {
        const int tok = sorted_ids[i0 + j];
        const float4* src = (const float4*)(x + (size_t)tok * HIDDEN);
        float4* dst = (float4*)(&xs[j][0]);
        for (int v = t; v < HIDDEN / 4; v += 256) dst[v] = src[v];
    }
    __syncthreads();

    const int r    = t & 15;
    const int g    = t >> 4;        // 16 h-groups
    const int wave = t >> 6;
    const int HC   = HIDDEN / 16;   // 128 k-iterations

    for (int m = 0; m < NMOD; ++m) {
        const float* Ap = A + ((size_t)m * NSLOT + s) * HIDDEN * MAXR;
        float a0 = 0.f, a1 = 0.f, a2 = 0.f, a3 = 0.f;
        #pragma unroll 8
        for (int k = 0; k < HC; ++k) {
            const int h = 16 * k + g;
            const float a = Ap[256 * k + t];   // == Ap[h*MAXR + r]
            a0 += xs[0][h] * a;
            a1 += xs[1][h] * a;
            a2 += xs[2][h] * a;
            a3 += xs[3][h] * a;
        }
        // reduce over the wave's 4 g-values (bits 4,5 of t)
        a0 += __shfl_xor(a0, 16); a0 += __shfl_xor(a0, 32);
        a1 += __shfl_xor(a1, 16); a1 += __shfl_xor(a1, 32);
        a2 += __shfl_xor(a2, 16); a2 += __shfl_xor(a2, 32);
        a3 += __shfl_xor(a3, 16); a3 += __shfl_xor(a3, 32);
        if ((t & 63) < 16) {
            red[wave][0][r] = a0;
            red[wave][1][r] = a1;
            red[wave][2][r] = a2;
            red[wave][3][r] = a3;
        }
        __syncthreads();
        if (t < 64) {
            const int j = t >> 4, rr = t & 15;
            float v = red[0][j][rr] + red[1][j][rr] + red[2][j][rr] + red[3][j][rr];
            if (rr >= R) v = 0.f;   // rank mask -> expand kernel needs no mask
            inter[((size_t)m * BS + (i0 + j)) * MAXR + rr] = v;
        }
        __syncthreads();   // red reused next m
    }
}

// ---------------------------------------------------------------------------
// Kernel 2: expand. out[i][m*OUTW + c] = sum_r inter[m][i][r] * B[m,s,r,c]
// Block = (m, s, 1024-col tile, 64-row chunk). Each thread caches its
// 16 x float4 B slab in registers and streams 64 rows (uniform inter loads,
// coalesced float4 stores). inter is rank-masked, so always 16 FMAs.
// ---------------------------------------------------------------------------
__global__ __launch_bounds__(256) void lora_expand(
    const float* __restrict__ inter,
    const float* __restrict__ B,
    const int*   __restrict__ slot_offsets,
    const int*   __restrict__ slot_counts,
    float*       __restrict__ out)
{
    int b = blockIdx.x;
    const int rc = b & 7; b >>= 3;       // row chunk   (8 x 64 rows)
    const int ct = b & 7; b >>= 3;       // col tile    (8 x 1024 cols)
    const int s  = b & 7; const int m = b >> 3;
    const int t  = threadIdx.x;

    const int row0   = slot_offsets[s] + rc * 64;
    const int rowEnd = slot_offsets[s] + slot_counts[s];
    const int rend   = min(row0 + 64, rowEnd);

    const int c0 = ct * 1024 + t * 4;
    const float* Bp = B + ((size_t)m * NSLOT + s) * MAXR * OUTW + c0;

    float4 breg[MAXR];
    #pragma unroll
    for (int rr = 0; rr < MAXR; ++rr)
        breg[rr] = *(const float4*)(Bp + (size_t)rr * OUTW);

    for (int i = row0; i < rend; ++i) {
        const float* ip = inter + ((size_t)m * BS + i) * MAXR;  // block-uniform
        const float4 w0 = *(const float4*)(ip);
        const float4 w1 = *(const float4*)(ip + 4);
        const float4 w2 = *(const float4*)(ip + 8);
        const float4 w3 = *(const float4*)(ip + 12);
        const float iv[MAXR] = {w0.x,w0.y,w0.z,w0.w, w1.x,w1.y,w1.z,w1.w,
                                w2.x,w2.y,w2.z,w2.w, w3.x,w3.y,w3.z,w3.w};
        float4 acc = make_float4(0.f, 0.f, 0.f, 0.f);
        #pragma unroll
        for (int rr = 0; rr < MAXR; ++rr) {
            acc.x += iv[rr] * breg[rr].x;
            acc.y += iv[rr] * breg[rr].y;
            acc.z += iv[rr] * breg[rr].z;
            acc.w += iv[rr] * breg[rr].w;
        }
        *(float4*)(out + (size_t)i * (NMOD * OUTW) + (size_t)m * OUTW + c0) = acc;
    }
}

extern "C" void kernel_launch(void* const* d_in, const int* in_sizes, int n_in,
                              void* d_out, int out_size, void* d_ws, size_t ws_size,
                              hipStream_t stream)
{
    const float* x            = (const float*)d_in[0];
    const float* A            = (const float*)d_in[1];
    const float* B            = (const float*)d_in[2];
    const int*   sorted_ids   = (const int*)d_in[3];
    const int*   slot_counts  = (const int*)d_in[4];
    const int*   slot_ranks   = (const int*)d_in[5];
    const int*   slot_offsets = (const int*)d_in[6];
    float*       out          = (float*)d_out;
    float*       inter        = (float*)d_ws;   // NMOD*BS*MAXR*4 = 512 KiB

    hipLaunchKernelGGL(lora_shrink, dim3(BS / 4), dim3(256), 0, stream,
                       x, A, sorted_ids, slot_ranks, slot_offsets, inter);
    hipLaunchKernelGGL(lora_expand, dim3(NMOD * NSLOT * 8 * 8), dim3(256), 0, stream,
                       inter, B, slot_offsets, slot_counts, out);
}

// Round 2
// 92.526 us; speedup vs baseline: 1.3998x; 1.3998x over previous
//
#include <hip/hip_runtime.h>

#define BS     4096
#define HIDDEN 2048
#define MAXR   16
#define NSLOT  8
#define NMOD   2
#define OUTW   8192

typedef float f4 __attribute__((ext_vector_type(4)));

// ---------------------------------------------------------------------------
// Kernel 1: shrink. inter[m][i][r] = sum_h x[sorted_ids[i]][h] * A[m,s,h,r]
// Block = 8 rows (one slot; 8 | 512). Thread t: hq = t>>2 (h-quad), q = t&3
// (r-quad, r = 4q..4q+3). Per k-step (256 h per block-iter):
//   - 8x ds_read_b128 of x (contiguous 16B chunks, 2-way alias = free)
//   - 8x float4 A loads (64B segments, L2-resident A)
//   - 256 FMAs (both modules) -> FMA : LDS-instr = 32 : 1
// x LDS reads amortized over BOTH modules in a single pass.
// Reduction: 2-step shfl_xor over lane bits 2,3; 16 KiB red scratch ALIASED
// into the xs LDS region (xs dead after compute) -> exactly 64 KiB static.
// ---------------------------------------------------------------------------
__global__ __launch_bounds__(256) void lora_shrink(
    const float* __restrict__ x,
    const float* __restrict__ A,
    const int*   __restrict__ sorted_ids,
    const int*   __restrict__ slot_ranks,
    const int*   __restrict__ slot_offsets,
    float*       __restrict__ inter)
{
    __shared__ float smem[8 * HIDDEN];   // 64 KiB: xs during compute, red after
    const int t  = threadIdx.x;
    const int i0 = blockIdx.x * 8;

    int s = 0;
    #pragma unroll
    for (int k = 1; k < NSLOT; ++k) if (i0 >= slot_offsets[k]) s = k;

    // stage 8 gathered x rows (coalesced float4)
    #pragma unroll
    for (int j = 0; j < 8; ++j) {
        const int tok = sorted_ids[i0 + j];
        const f4* src = (const f4*)(x + (size_t)tok * HIDDEN);
        f4* dst = (f4*)(smem + j * HIDDEN);
        dst[t]       = src[t];
        dst[t + 256] = src[t + 256];
    }
    __syncthreads();

    const int hq = t >> 2;   // 0..63
    const int q  = t & 3;

    f4 acc[NMOD][8];
    #pragma unroll
    for (int m = 0; m < NMOD; ++m)
        #pragma unroll
        for (int j = 0; j < 8; ++j) acc[m][j] = (f4)(0.f);

    const f4* A4 = (const f4*)A;

    #pragma unroll 2
    for (int k = 0; k < 8; ++k) {
        f4 xv[8];
        #pragma unroll
        for (int j = 0; j < 8; ++j)
            xv[j] = *(const f4*)(smem + j * HIDDEN + 256 * k + 4 * hq);
        #pragma unroll
        for (int m = 0; m < NMOD; ++m) {
            const f4* Ap = A4 + (size_t)(m * NSLOT + s) * (HIDDEN * MAXR / 4)
                              + 1024 * k + 16 * hq;
            const f4 a0 = Ap[q];      // A row h0+0, cols 4q..4q+3
            const f4 a1 = Ap[4 + q];  // row h0+1
            const f4 a2 = Ap[8 + q];  // row h0+2
            const f4 a3 = Ap[12 + q]; // row h0+3
            #pragma unroll
            for (int j = 0; j < 8; ++j) {
                const f4 v = xv[j];
                acc[m][j] += v.x * a0 + v.y * a1 + v.z * a2 + v.w * a3;
            }
        }
    }

    __syncthreads();   // all waves done reading xs before aliasing as red

    // butterfly over lane bits 2,3 (low hq bits)
    #pragma unroll
    for (int m = 0; m < NMOD; ++m)
        #pragma unroll
        for (int j = 0; j < 8; ++j) {
            f4 a = acc[m][j];
            a.x += __shfl_xor(a.x, 4); a.y += __shfl_xor(a.y, 4);
            a.z += __shfl_xor(a.z, 4); a.w += __shfl_xor(a.w, 4);
            a.x += __shfl_xor(a.x, 8); a.y += __shfl_xor(a.y, 8);
            a.z += __shfl_xor(a.z, 8); a.w += __shfl_xor(a.w, 8);
            acc[m][j] = a;
        }

    // lanes with (lane & 12) == 0 hold group sums; g = hq high bits
    if ((t & 12) == 0) {
        const int w = t >> 6, g = (t >> 4) & 3;
        #pragma unroll
        for (int m = 0; m < NMOD; ++m)
            #pragma unroll
            for (int j = 0; j < 8; ++j)
                *(f4*)(smem + ((((m * 4 + w) * 4 + g) * 8 + j) * 16 + 4 * q)) = acc[m][j];
    }
    __syncthreads();

    // final: one (m, j, r) per thread; sum 16 partials, rank-mask, store
    {
        const int m = t >> 7, j = (t >> 4) & 7, r = t & 15;
        float v = 0.f;
        #pragma unroll
        for (int w = 0; w < 4; ++w)
            #pragma unroll
            for (int g = 0; g < 4; ++g)
                v += smem[(((m * 4 + w) * 4 + g) * 8 + j) * 16 + r];
        if (r >= slot_ranks[s]) v = 0.f;   // rank mask -> expand needs no mask
        inter[((size_t)m * BS + (i0 + j)) * MAXR + r] = v;
    }
}

// ---------------------------------------------------------------------------
// Kernel 2: expand. out[i][m*OUTW + c] = sum_r inter[m][i][r] * B[m,s,r,c]
// Block = (m, s, 1024-col tile, 64-row chunk). Each thread caches its
// 16 x f4 B slab in registers, streams 64 rows (uniform inter loads,
// coalesced NON-TEMPORAL float4 stores -- output is write-once, 268 MB).
// ---------------------------------------------------------------------------
__global__ __launch_bounds__(256) void lora_expand(
    const float* __restrict__ inter,
    const float* __restrict__ B,
    const int*   __restrict__ slot_offsets,
    const int*   __restrict__ slot_counts,
    float*       __restrict__ out)
{
    int b = blockIdx.x;
    const int rc = b & 7; b >>= 3;       // row chunk   (8 x 64 rows)
    const int ct = b & 7; b >>= 3;       // col tile    (8 x 1024 cols)
    const int s  = b & 7; const int m = b >> 3;
    const int t  = threadIdx.x;

    const int row0   = slot_offsets[s] + rc * 64;
    const int rowEnd = slot_offsets[s] + slot_counts[s];
    const int rend   = min(row0 + 64, rowEnd);

    const int c0 = ct * 1024 + t * 4;
    const float* Bp = B + ((size_t)m * NSLOT + s) * MAXR * OUTW + c0;

    f4 breg[MAXR];
    #pragma unroll
    for (int rr = 0; rr < MAXR; ++rr)
        breg[rr] = *(const f4*)(Bp + (size_t)rr * OUTW);

    for (int i = row0; i < rend; ++i) {
        const float* ip = inter + ((size_t)m * BS + i) * MAXR;  // block-uniform
        const f4 w0 = *(const f4*)(ip);
        const f4 w1 = *(const f4*)(ip + 4);
        const f4 w2 = *(const f4*)(ip + 8);
        const f4 w3 = *(const f4*)(ip + 12);
        f4 acc = (f4)(0.f);
        acc += w0.x * breg[0]  + w0.y * breg[1]  + w0.z * breg[2]  + w0.w * breg[3];
        acc += w1.x * breg[4]  + w1.y * breg[5]  + w1.z * breg[6]  + w1.w * breg[7];
        acc += w2.x * breg[8]  + w2.y * breg[9]  + w2.z * breg[10] + w2.w * breg[11];
        acc += w3.x * breg[12] + w3.y * breg[13] + w3.z * breg[14] + w3.w * breg[15];
        __builtin_nontemporal_store(acc,
            (f4*)(out + (size_t)i * (NMOD * OUTW) + (size_t)m * OUTW + c0));
    }
}

extern "C" void kernel_launch(void* const* d_in, const int* in_sizes, int n_in,
                              void* d_out, int out_size, void* d_ws, size_t ws_size,
                              hipStream_t stream)
{
    const float* x            = (const float*)d_in[0];
    const float* A            = (const float*)d_in[1];
    const float* B            = (const float*)d_in[2];
    const int*   sorted_ids   = (const int*)d_in[3];
    const int*   slot_counts  = (const int*)d_in[4];
    const int*   slot_ranks   = (const int*)d_in[5];
    const int*   slot_offsets = (const int*)d_in[6];
    float*       out          = (float*)d_out;
    float*       inter        = (float*)d_ws;   // NMOD*BS*MAXR*4 = 512 KiB

    hipLaunchKernelGGL(lora_shrink, dim3(BS / 8), dim3(256), 0, stream,
                       x, A, sorted_ids, slot_ranks, slot_offsets, inter);
    hipLaunchKernelGGL(lora_expand, dim3(NMOD * NSLOT * 8 * 8), dim3(256), 0, stream,
                       inter, B, slot_offsets, slot_counts, out);
}

// Round 3
// 65.244 us; speedup vs baseline: 1.9851x; 1.4182x over previous
//
#include <hip/hip_runtime.h>

#define BS     4096
#define HIDDEN 2048
#define MAXR   16
#define NSLOT  8
#define NMOD   2
#define OUTW   8192
#define ROWS   8

typedef float f4 __attribute__((ext_vector_type(4)));

// ---------------------------------------------------------------------------
// Expand phase, templated on rank-quads RQ = ceil(R/4) so breg indexing stays
// compile-time (runtime-indexed ext_vector arrays go to scratch).
// Per 1024-col tile: cache B slab (RQ*4 x f4) in regs, stream 8 rows:
// uniform LDS inter reads (broadcast), 16*RQ f4 FMAs, one NT float4 store.
// ---------------------------------------------------------------------------
template<int RQ>
__device__ __forceinline__ void expand_tiles(
    const float* __restrict__ B, const float* inter_s,
    float* __restrict__ out, int s, int i0, int t)
{
    #pragma unroll 1
    for (int ct = 0; ct < 16; ++ct) {
        const int m  = ct >> 3;
        const int c0 = (ct & 7) * 1024 + t * 4;
        const float* Bp = B + ((size_t)(m * NSLOT + s) * MAXR) * OUTW + c0;
        f4 breg[RQ * 4];
        #pragma unroll
        for (int r = 0; r < RQ * 4; ++r)
            breg[r] = *(const f4*)(Bp + (size_t)r * OUTW);
        #pragma unroll
        for (int j = 0; j < ROWS; ++j) {
            const float* ip = inter_s + (m * ROWS + j) * MAXR;
            f4 acc = (f4)(0.f);
            #pragma unroll
            for (int rq = 0; rq < RQ; ++rq) {
                const f4 w = *(const f4*)(ip + 4 * rq);
                acc += w.x * breg[4*rq+0] + w.y * breg[4*rq+1]
                     + w.z * breg[4*rq+2] + w.w * breg[4*rq+3];
            }
            __builtin_nontemporal_store(acc,
                (f4*)(out + (size_t)(i0 + j) * (NMOD * OUTW) + (size_t)m * OUTW + c0));
        }
    }
}

// ---------------------------------------------------------------------------
// Fused LoRA: block = 8 rows (one slot) x all 16384 out cols.
// Phase 1 (shrink): thread t = (hq = t>>2, q = t&3). Per k-step: 8 f4 x-loads
// (4 lanes share addr -> one 256B fetch, no redundancy), 2x4 f4 A-loads,
// 256 FMAs. Butterfly over lane bits 2,3 -> red LDS -> final reduce writes
// rank-masked inter to 1 KB LDS. No global inter round-trip.
// Phase 2 (expand): rank-templated streaming stores (above).
// XCD swizzle maps slot s -> XCD s so each XCD's L2 holds its 1 MB B panel.
// ---------------------------------------------------------------------------
__global__ __launch_bounds__(256) void lora_fused(
    const float* __restrict__ x,
    const float* __restrict__ A,
    const float* __restrict__ B,
    const int*   __restrict__ sorted_ids,
    const int*   __restrict__ slot_ranks,
    const int*   __restrict__ slot_offsets,
    float*       __restrict__ out)
{
    __shared__ float red[NMOD * 4 * 4 * ROWS * MAXR];   // 16 KiB (m,w,g,j,r)
    __shared__ float inter_s[NMOD * ROWS * MAXR];       // 1 KiB

    const int t = threadIdx.x;
    // slot->XCD swizzle: hw block i -> logical (i%8)*64 + i/8 (512 blocks)
    const int bid = (blockIdx.x & 7) * 64 + (blockIdx.x >> 3);
    const int i0  = bid * ROWS;

    int s = 0;
    #pragma unroll
    for (int k = 1; k < NSLOT; ++k) if (i0 >= slot_offsets[k]) s = k;

    int tok[ROWS];
    #pragma unroll
    for (int j = 0; j < ROWS; ++j) tok[j] = sorted_ids[i0 + j];   // uniform -> s_load

    const int hq = t >> 2;   // 0..63 : h-quad
    const int q  = t & 3;    // r-quad (r = 4q..4q+3)

    f4 acc[NMOD][ROWS];
    #pragma unroll
    for (int m = 0; m < NMOD; ++m)
        #pragma unroll
        for (int j = 0; j < ROWS; ++j) acc[m][j] = (f4)(0.f);

    #pragma unroll 1
    for (int k = 0; k < 8; ++k) {
        f4 xv[ROWS];
        #pragma unroll
        for (int j = 0; j < ROWS; ++j)
            xv[j] = *(const f4*)(x + (size_t)tok[j] * HIDDEN + 256 * k + 4 * hq);
        #pragma unroll
        for (int m = 0; m < NMOD; ++m) {
            const float* Ap = A + (size_t)(m * NSLOT + s) * (HIDDEN * MAXR)
                                + 4096 * k + 64 * hq + 4 * q;
            const f4 a0 = *(const f4*)(Ap);
            const f4 a1 = *(const f4*)(Ap + 16);
            const f4 a2 = *(const f4*)(Ap + 32);
            const f4 a3 = *(const f4*)(Ap + 48);
            #pragma unroll
            for (int j = 0; j < ROWS; ++j) {
                const f4 v = xv[j];
                acc[m][j] += v.x * a0 + v.y * a1 + v.z * a2 + v.w * a3;
            }
        }
    }

    // butterfly over lane bits 2,3 (low bits of hq)
    #pragma unroll
    for (int m = 0; m < NMOD; ++m)
        #pragma unroll
        for (int j = 0; j < ROWS; ++j) {
            f4 a = acc[m][j];
            a.x += __shfl_xor(a.x, 4); a.y += __shfl_xor(a.y, 4);
            a.z += __shfl_xor(a.z, 4); a.w += __shfl_xor(a.w, 4);
            a.x += __shfl_xor(a.x, 8); a.y += __shfl_xor(a.y, 8);
            a.z += __shfl_xor(a.z, 8); a.w += __shfl_xor(a.w, 8);
            acc[m][j] = a;
        }

    if ((t & 12) == 0) {
        const int w = t >> 6, g = (t >> 4) & 3;
        #pragma unroll
        for (int m = 0; m < NMOD; ++m)
            #pragma unroll
            for (int j = 0; j < ROWS; ++j)
                *(f4*)(red + (((m * 4 + w) * 4 + g) * ROWS + j) * MAXR + 4 * q) = acc[m][j];
    }
    __syncthreads();

    {   // final reduce: one (m, j, r) per thread; rank-mask; write LDS inter
        const int m = t >> 7, j = (t >> 4) & 7, r = t & 15;
        float v = 0.f;
        #pragma unroll
        for (int w = 0; w < 4; ++w)
            #pragma unroll
            for (int g = 0; g < 4; ++g)
                v += red[(((m * 4 + w) * 4 + g) * ROWS + j) * MAXR + r];
        if (r >= slot_ranks[s]) v = 0.f;
        inter_s[(m * ROWS + j) * MAXR + r] = v;
    }
    __syncthreads();

    const int rq = (slot_ranks[s] + 3) >> 2;
    switch (rq) {
        case 1:  expand_tiles<1>(B, inter_s, out, s, i0, t); break;
        case 2:  expand_tiles<2>(B, inter_s, out, s, i0, t); break;
        case 3:  expand_tiles<3>(B, inter_s, out, s, i0, t); break;
        default: expand_tiles<4>(B, inter_s, out, s, i0, t); break;
    }
}

extern "C" void kernel_launch(void* const* d_in, const int* in_sizes, int n_in,
                              void* d_out, int out_size, void* d_ws, size_t ws_size,
                              hipStream_t stream)
{
    const float* x            = (const float*)d_in[0];
    const float* A            = (const float*)d_in[1];
    const float* B            = (const float*)d_in[2];
    const int*   sorted_ids   = (const int*)d_in[3];
    const int*   slot_ranks   = (const int*)d_in[5];
    const int*   slot_offsets = (const int*)d_in[6];
    float*       out          = (float*)d_out;

    hipLaunchKernelGGL(lora_fused, dim3(BS / ROWS), dim3(256), 0, stream,
                       x, A, B, sorted_ids, slot_ranks, slot_offsets, out);
}